// Round 9
// baseline (5489.370 us; speedup 1.0000x reference)
//
#include <hip/hip_runtime.h>
#include <cstdint>
#include <cstddef>

typedef __attribute__((ext_vector_type(8))) short short8;
typedef __attribute__((ext_vector_type(4))) float floatx4;

constexpr int kSeq = 512;
constexpr int kBatch = 256;
constexpr int kIn = 15;
constexpr int kH = 512;
constexpr int kG = 4 * kH;                      // 2048 gate cols, order i,f,g,o
constexpr int kRing = 17;                       // ring depth (> window 16)
constexpr size_t kHSlot = (size_t)kBatch * kH;  // elements per h slot
// LDS: 132 fragment-slabs (whh1 0..63, wih1 64..67, whh2 68..131) x 512 shorts
// + 4 waves x 768 shorts transpose scratch = 135168 + 6144 B
constexpr size_t kShmemBytes = 141312;

__device__ __forceinline__ unsigned short f2bf(float f) {
    union { float f; unsigned u; } v; v.f = f;
    unsigned u = v.u;
    return (unsigned short)((u + 0x7fffu + ((u >> 16) & 1u)) >> 16);
}

__device__ __forceinline__ float sigm(float x) { return 1.0f / (1.0f + __expf(-x)); }
__device__ __forceinline__ float tanh_(float x) { return 1.0f - 2.0f / (1.0f + __expf(2.0f * x)); }

// 16-B write-through store (LLC always current; h never dirty in any L2)
#define LLC_STORE16(P, V)                                                     \
    asm volatile("global_store_dwordx4 %0, %1, off sc0 sc1"                   \
                 :: "v"(P), "v"(V) : "memory")

// All-lane flag wait (r5-proven): every lane watches line (lane&31) (64B
// apart). Bounded busy-spin, s_sleep backoff past 4096. fc caches the
// monotone flag value so satisfied waits do zero memory ops.
__device__ __forceinline__ void waitf(const int* flags, int tgt, int lane, int& fc) {
    if (tgt <= 0) return;
    const int* myf = flags + (lane & 31) * 16;
    int spin = 0;
    while (!__all(fc >= tgt)) {
        if (fc < tgt)
            fc = __hip_atomic_load(myf, __ATOMIC_RELAXED, __HIP_MEMORY_SCOPE_AGENT);
        if (++spin > 4096) __builtin_amdgcn_s_sleep(8);
    }
}

__global__ void k_conv(const float* __restrict__ src, unsigned short* __restrict__ dst, int n) {
    int i = blockIdx.x * blockDim.x + threadIdx.x;
    if (i < n) dst[i] = f2bf(src[i]);
}

__global__ void k_conv_pad(const float* __restrict__ src, unsigned short* __restrict__ dst, int rows) {
    int i = blockIdx.x * blockDim.x + threadIdx.x;
    if (i >= rows * 32) return;
    int r = i >> 5, k = i & 31;
    dst[i] = (k < kIn) ? f2bf(src[r * kIn + k]) : (unsigned short)0;
}

// MERGED-LAYER persistent kernel: 128 blocks. group g = blockIdx&3 (64 batch
// rows, wave w owns rows g*64+w*16); role rid = blockIdx>>2 (0..31) owns
// h-cols [16*rid, 16*rid+16) of BOTH layers.
//
// Round t (t = 0..511): all peers' round t-1 outputs {h1[t], h2[t-1]} were
// published together under flag t+1. Round t: ONE wait (flag >= t+1) ->
// load h1[t] once (feeds whh1-GEMM and wih2-GEMM) + h2[t-1] -> compute
// h2[t] = lstm2(h1[t], h2[t-1]) and h1[t+1] = lstm1(x[t+1], h1[t]) ->
// store both (sc0sc1 write-through) -> drain -> publish flag t+2.
// Pre-round computes h1[0] from x[0] (h=0: no peer dependency), publishes 1.
//
// Rings: round t writes slot t%17 (both h1[t+1] and h2[t]); round t+1 reads
// slot (t+17-1)%17 = t%17. Each address re-read every 17 rounds; fence
// (acquire agent, invalidates L1/L2) every 16 rounds => no stale reads.
// Flag-wait bounds skew to 1 round => no write-during-read hazards.
// wih2 (64KB/block) does not fit LDS alongside whh1+whh2: streamed from
// global per round (constant addresses, L2-resident, per-gg 16-load bursts).
__global__ __launch_bounds__(256) void k_persist(
    const unsigned short* __restrict__ whh1b,
    const unsigned short* __restrict__ wih1b,
    const unsigned short* __restrict__ wih2b,
    const unsigned short* __restrict__ whh2b,
    const unsigned short* __restrict__ xb,
    const float* __restrict__ bih1, const float* __restrict__ bhh1,
    const float* __restrict__ bih2, const float* __restrict__ bhh2,
    unsigned short* __restrict__ h1r,   // kRing slots of kBatch*kH
    unsigned short* __restrict__ h2r,   // kRing slots of kBatch*kH
    float* __restrict__ h2f,
    int* __restrict__ flags)            // per group: 32 lines (stride 16 ints)
{
    extern __shared__ unsigned short lw[];
    const int bid = blockIdx.x;
    const int g = bid & 3;
    const int rid = bid >> 2;
    const int j0 = rid << 4;
    const int tid = (int)threadIdx.x;
    const int wave = tid >> 6;
    const int lane = tid & 63;
    const int lcol = lane & 15;
    const int quad = lane >> 4;
    const int m0 = (g << 6) + wave * 16;
    const int arow = m0 + lcol;
    const int koff = quad * 8;

    int* f = flags + g * 512;
    int* myflag = f + rid * 16;
    unsigned short* scr = lw + 67584 + wave * 768;   // [0..383] h2, [384..767] h1

    // ---- stage whh1 (slabs 0..63), wih1 (64..67), whh2 (68..131) ----
    for (int i = tid; i < 4096; i += 256) {
        int ln = i >> 6, gg = ln >> 4, u = ln & 15;
        int c = i & 63, kk = c >> 2, qd = c & 3;
        int dst = ((gg * 16 + kk) << 9) + ((qd * 16 + u) << 3);
        size_t src = (size_t)((gg << 9) + j0 + u) * kH + c * 8;
        *(short8*)&lw[dst] = *(const short8*)&whh1b[src];
        *(short8*)&lw[dst + (68 << 9)] = *(const short8*)&whh2b[src];
    }
    for (int i = tid; i < 256; i += 256) {
        int ln = i >> 2, gg = ln >> 4, u = ln & 15;
        int qd = i & 3;
        *(short8*)&lw[((64 + gg) << 9) + ((qd * 16 + u) << 3)] =
            *(const short8*)&wih1b[((gg << 9) + j0 + u) * 32 + qd * 8];
    }
    float bsum1[4], bsum2[4];
#pragma unroll
    for (int gg = 0; gg < 4; ++gg) {
        int n = (gg << 9) + j0 + lcol;
        bsum1[gg] = bih1[n] + bhh1[n];
        bsum2[gg] = bih2[n] + bhh2[n];
    }
    // per-lane base into wih2b for streamed B-fragments:
    // frag(gg,kk) = wih2b[((gg<<9)+j0+(lane&15))*512 + kk*32 + (lane>>4)*8 ..+8]
    const unsigned short* wstream = wih2b + (size_t)(j0 + lcol) * kH + koff;
    __syncthreads();

    float creg1[4] = {0.f, 0.f, 0.f, 0.f};
    float creg2[4] = {0.f, 0.f, 0.f, 0.f};
    int fc = 0;

    // ---- pre-round: h1[0] = lstm1(x[0], h=0, c=0) -> slot 16, flag 1 ----
    {
        floatx4 acc[4];
#pragma unroll
        for (int gg = 0; gg < 4; ++gg)
            acc[gg] = (floatx4){bsum1[gg], bsum1[gg], bsum1[gg], bsum1[gg]};
        short8 ax = *(const short8*)(xb + (size_t)arow * 32 + koff);
#pragma unroll
        for (int gg = 0; gg < 4; ++gg) {
            short8 b = *(const short8*)&lw[((64 + gg) << 9) + (lane << 3)];
            acc[gg] = __builtin_amdgcn_mfma_f32_16x16x32_bf16(ax, b, acc[gg], 0, 0, 0);
        }
        unsigned short* hw = h1r + (size_t)16 * kHSlot;
#pragma unroll
        for (int r = 0; r < 4; ++r) {
            int row = quad * 4 + r;
            float gi = acc[0][r], gf = acc[1][r], gv = acc[2][r], go = acc[3][r];
            float cn = sigm(gf) * creg1[r] + sigm(gi) * tanh_(gv);
            float hn = sigm(go) * tanh_(cn);
            creg1[r] = cn;
            scr[384 + row * 24 + lcol] = f2bf(hn);
        }
        if (lane < 32) {
            int row = lane >> 1, seg = lane & 1;
            short8 v = *(short8*)&scr[384 + row * 24 + seg * 8];
            unsigned short* gp = hw + (size_t)(m0 + row) * kH + j0 + seg * 8;
            LLC_STORE16(gp, v);
        }
        __builtin_amdgcn_s_waitcnt(0);
        __syncthreads();
        if (tid == 0)
            __hip_atomic_store(myflag, 1, __ATOMIC_RELAXED, __HIP_MEMORY_SCOPE_AGENT);
    }

    // ---- rounds 0..511 ----
    for (int t = 0; t < kSeq; ++t) {
        waitf(f, t + 1, lane, fc);
        if ((t & 15) == 0)
            __builtin_amdgcn_fence(__ATOMIC_ACQUIRE, "agent");

        const int sr = (t + 16) % kRing;   // read slot (round t-1's outputs)
        const int sw = t % kRing;          // write slot
        const unsigned short* hp1 = h1r + (size_t)sr * kHSlot + (size_t)arow * kH + koff;
        const unsigned short* hp2 = h2r + (size_t)sr * kHSlot + (size_t)arow * kH + koff;
        short8 a1[16], a2[16];
#pragma unroll
        for (int kk = 0; kk < 16; ++kk) a2[kk] = *(const short8*)(hp2 + kk * 32);
#pragma unroll
        for (int kk = 0; kk < 16; ++kk) a1[kk] = *(const short8*)(hp1 + kk * 32);

        floatx4 acc2[4];
#pragma unroll
        for (int gg = 0; gg < 4; ++gg)
            acc2[gg] = (floatx4){bsum2[gg], bsum2[gg], bsum2[gg], bsum2[gg]};

        // layer-2: h2[t-1] @ whh2 (LDS slabs 68..131)
#pragma unroll
        for (int kk = 0; kk < 16; ++kk) {
#pragma unroll
            for (int gg = 0; gg < 4; ++gg) {
                short8 b = *(const short8*)&lw[((68 + gg * 16 + kk) << 9) + (lane << 3)];
                acc2[gg] = __builtin_amdgcn_mfma_f32_16x16x32_bf16(a2[kk], b, acc2[gg], 0, 0, 0);
            }
        }
        // layer-2: h1[t] @ wih2 (streamed from global, per-gg 16-load bursts)
#pragma unroll
        for (int gg = 0; gg < 4; ++gg) {
            const unsigned short* wp = wstream + (size_t)gg * (512 * 512);
            short8 bfr[16];
#pragma unroll
            for (int kk = 0; kk < 16; ++kk) bfr[kk] = *(const short8*)(wp + kk * 32);
#pragma unroll
            for (int kk = 0; kk < 16; ++kk)
                acc2[gg] = __builtin_amdgcn_mfma_f32_16x16x32_bf16(a1[kk], bfr[kk], acc2[gg], 0, 0, 0);
        }

        // layer-1: h1[t+1] = lstm1(x[t+1], h1[t])  (skip at t==511)
        floatx4 acc1[4];
        if (t < kSeq - 1) {
#pragma unroll
            for (int gg = 0; gg < 4; ++gg)
                acc1[gg] = (floatx4){bsum1[gg], bsum1[gg], bsum1[gg], bsum1[gg]};
            short8 ax = *(const short8*)(xb + ((size_t)(t + 1) * kBatch + arow) * 32 + koff);
#pragma unroll
            for (int kk = 0; kk < 16; ++kk) {
#pragma unroll
                for (int gg = 0; gg < 4; ++gg) {
                    short8 b = *(const short8*)&lw[((gg * 16 + kk) << 9) + (lane << 3)];
                    acc1[gg] = __builtin_amdgcn_mfma_f32_16x16x32_bf16(a1[kk], b, acc1[gg], 0, 0, 0);
                }
            }
#pragma unroll
            for (int gg = 0; gg < 4; ++gg) {
                short8 b = *(const short8*)&lw[((64 + gg) << 9) + (lane << 3)];
                acc1[gg] = __builtin_amdgcn_mfma_f32_16x16x32_bf16(ax, b, acc1[gg], 0, 0, 0);
            }
        }

        // epilogue layer-2 -> scr[0..383]
        unsigned short* hw2 = h2r + (size_t)sw * kHSlot;
        const int j = j0 + lcol;
#pragma unroll
        for (int r = 0; r < 4; ++r) {
            int row = quad * 4 + r;
            float gi = acc2[0][r], gf = acc2[1][r], gv = acc2[2][r], go = acc2[3][r];
            float cn = sigm(gf) * creg2[r] + sigm(gi) * tanh_(gv);
            float hn = sigm(go) * tanh_(cn);
            creg2[r] = cn;
            scr[row * 24 + lcol] = f2bf(hn);
            if (t == kSeq - 1) h2f[(size_t)(m0 + row) * kH + j] = hn;
        }
        // epilogue layer-1 -> scr[384..767]
        unsigned short* hw1 = h1r + (size_t)sw * kHSlot;
        if (t < kSeq - 1) {
#pragma unroll
            for (int r = 0; r < 4; ++r) {
                int row = quad * 4 + r;
                float gi = acc1[0][r], gf = acc1[1][r], gv = acc1[2][r], go = acc1[3][r];
                float cn = sigm(gf) * creg1[r] + sigm(gi) * tanh_(gv);
                float hn = sigm(go) * tanh_(cn);
                creg1[r] = cn;
                scr[384 + row * 24 + lcol] = f2bf(hn);
            }
        }
        if (lane < 32) {
            int row = lane >> 1, seg = lane & 1;
            short8 v2 = *(short8*)&scr[row * 24 + seg * 8];
            unsigned short* gp2 = hw2 + (size_t)(m0 + row) * kH + j0 + seg * 8;
            LLC_STORE16(gp2, v2);
            if (t < kSeq - 1) {
                short8 v1 = *(short8*)&scr[384 + row * 24 + seg * 8];
                unsigned short* gp1 = hw1 + (size_t)(m0 + row) * kH + j0 + seg * 8;
                LLC_STORE16(gp1, v1);
            }
        }
        if (t < kSeq - 1) {
            __builtin_amdgcn_s_waitcnt(0);
            __syncthreads();
            if (tid == 0)
                __hip_atomic_store(myflag, t + 2,
                                   __ATOMIC_RELAXED, __HIP_MEMORY_SCOPE_AGENT);
        }
    }
}

__global__ __launch_bounds__(64) void k_head(
    const float* __restrict__ h2f, const float* __restrict__ fc1w,
    const float* __restrict__ fc1b, const float* __restrict__ fcw,
    const float* __restrict__ fcb, float* __restrict__ out)
{
    int m = blockIdx.x;
    int j = threadIdx.x;
    const float* hr = h2f + (size_t)m * kH;
    const float* wr = fc1w + (size_t)j * kH;
    float sacc = 0.f;
    for (int k = 0; k < kH; ++k) sacc += fmaxf(hr[k], 0.f) * wr[k];
    float rv = fmaxf(sacc + fc1b[j], 0.f) * fcw[j];
#pragma unroll
    for (int off = 32; off >= 1; off >>= 1) rv += __shfl_down(rv, off);
    if (j == 0) out[m] = 2.0f * (rv + fcb[0]);
}

extern "C" void kernel_launch(void* const* d_in, const int* in_sizes, int n_in,
                              void* d_out, int out_size, void* d_ws, size_t ws_size,
                              hipStream_t stream) {
    const float* x    = (const float*)d_in[0];
    const float* Wih1 = (const float*)d_in[1];
    const float* Whh1 = (const float*)d_in[2];
    const float* bih1 = (const float*)d_in[3];
    const float* bhh1 = (const float*)d_in[4];
    const float* Wih2 = (const float*)d_in[5];
    const float* Whh2 = (const float*)d_in[6];
    const float* bih2 = (const float*)d_in[7];
    const float* bhh2 = (const float*)d_in[8];
    const float* fc1w = (const float*)d_in[9];
    const float* fc1b = (const float*)d_in[10];
    const float* fcw  = (const float*)d_in[11];
    const float* fcb  = (const float*)d_in[12];
    float* out = (float*)d_out;

    char* p = (char*)d_ws;
    auto take = [&](size_t bytes) -> char* {
        char* r = p;
        p += (bytes + 255) & ~(size_t)255;
        return r;
    };
    unsigned short* whh1b = (unsigned short*)take((size_t)kG * kH * 2);
    unsigned short* wih2b = (unsigned short*)take((size_t)kG * kH * 2);
    unsigned short* whh2b = (unsigned short*)take((size_t)kG * kH * 2);
    unsigned short* wih1b = (unsigned short*)take((size_t)kG * 32 * 2);
    unsigned short* xb    = (unsigned short*)take((size_t)kSeq * kBatch * 32 * 2);
    char* state = p;
    unsigned short* h1r = (unsigned short*)take((size_t)kRing * kHSlot * 2);
    unsigned short* h2r = (unsigned short*)take((size_t)kRing * kHSlot * 2);
    int* flags = (int*)take(16384);
    size_t state_bytes = (size_t)((char*)flags + 16384 - state);
    float* h2f = (float*)take((size_t)kBatch * kH * 4);

    hipMemsetAsync(state, 0, state_bytes, stream);

    int n = kG * kH;
    k_conv<<<(n + 255) / 256, 256, 0, stream>>>(Whh1, whh1b, n);
    k_conv<<<(n + 255) / 256, 256, 0, stream>>>(Wih2, wih2b, n);
    k_conv<<<(n + 255) / 256, 256, 0, stream>>>(Whh2, whh2b, n);
    k_conv_pad<<<(kG * 32 + 255) / 256, 256, 0, stream>>>(Wih1, wih1b, kG);
    k_conv_pad<<<(kSeq * kBatch * 32 + 255) / 256, 256, 0, stream>>>(x, xb, kSeq * kBatch);

    hipFuncSetAttribute((const void*)k_persist,
                        hipFuncAttributeMaxDynamicSharedMemorySize, (int)kShmemBytes);
    void* args[] = {&whh1b, &wih1b, &wih2b, &whh2b, &xb,
                    (void*)&bih1, (void*)&bhh1, (void*)&bih2, (void*)&bhh2,
                    &h1r, &h2r, &h2f, &flags};
    hipError_t e = hipLaunchCooperativeKernel((const void*)k_persist, dim3(128), dim3(256),
                                              args, (unsigned)kShmemBytes, stream);
    if (e != hipSuccess) {
        k_persist<<<128, 256, kShmemBytes, stream>>>(
            whh1b, wih1b, wih2b, whh2b, xb, bih1, bhh1, bih2, bhh2,
            h1r, h2r, h2f, flags);
    }

    k_head<<<kBatch, 64, 0, stream>>>(h2f, fc1w, fc1b, fcw, fcb, out);
}